// Round 9
// baseline (222.355 us; speedup 1.0000x reference)
//
#include <hip/hip_runtime.h>
#include <hip/hip_bf16.h>

typedef __attribute__((ext_vector_type(8))) short short8;
typedef __attribute__((ext_vector_type(4))) float f32x4;

// ws layout (bytes)
#define WFT_OFF 0          // bf16 image WfTi[16][256 cols][64 B swz] = 262144 B
#define HB_OFF  262144     // f32[32*256]             =  32768 B
#define SC_OFF  294912     // f32[131072] scores      = 524288 B
#define ST_OFF  819200     // f32[8192*2] m,l         =  65536 B
#define CP_OFF  884736     // f32[8192*512] ctx part  = 16777216 B (total ~17.7 MB, ws >= 142 MB proven R5)

// scores LDS: Ab f32 [16][2048B] swizzled @0 (32 KB),
//             Bb 8 waves x 3 bufs x 2 KB @32768 (48 KB, tail doubles as wpart)
#define SMEM_S 81920

__device__ __forceinline__ float bf2f(unsigned short h) {
    unsigned u = ((unsigned)h) << 16;
    return __builtin_bit_cast(float, u);
}
__device__ __forceinline__ unsigned pack_bf16(float a, float b) {
    unsigned short sa = __builtin_bit_cast(unsigned short, __float2bfloat16(a));
    unsigned short sb = __builtin_bit_cast(unsigned short, __float2bfloat16(b));
    return (unsigned)sa | ((unsigned)sb << 16);
}
__device__ __forceinline__ short8 cvt8(float4 a, float4 b) {
    union { unsigned u[4]; short8 s; } r;
    r.u[0] = pack_bf16(a.x, a.y); r.u[1] = pack_bf16(a.z, a.w);
    r.u[2] = pack_bf16(b.x, b.y); r.u[3] = pack_bf16(b.z, b.w);
    return r.s;
}
__device__ __forceinline__ float fast_tanh(float x) {
    float e2 = __expf(2.0f * x);
    return 1.0f - 2.0f / (e2 + 1.0f);
}
__device__ __forceinline__ void lds_barrier() {
    asm volatile("s_waitcnt lgkmcnt(0)" ::: "memory");
    __builtin_amdgcn_s_barrier();
}
// async global->LDS, 16 B/lane; LDS dest = wave-uniform base + lane*16
__device__ __forceinline__ void gld_lds16(const char* g, char* l) {
    __builtin_amdgcn_global_load_lds(
        (const __attribute__((address_space(1))) void*)g,
        (__attribute__((address_space(3))) void*)l, 16, 0, 0);
}

// ---- Wf (512x256 f32) -> bf16 image [ks][col][64B] (R8-proven, unchanged) ----
__global__ void wft_kernel(const float* __restrict__ Wf, unsigned short* __restrict__ WfTi) {
    __shared__ unsigned short tl[64 * 80];
    const int t = threadIdx.x;
    const int tk = blockIdx.x >> 2, ta = blockIdx.x & 3;
    const int d0 = tk * 64, a0 = ta * 64;
#pragma unroll
    for (int i = 0; i < 16; ++i) {
        int flat = t + 256 * i;
        int dl = flat >> 6, al = flat & 63;
        tl[al * 80 + dl] = __builtin_bit_cast(unsigned short,
                               __float2bfloat16(Wf[(d0 + dl) * 256 + a0 + al]));
    }
    __syncthreads();
    uint4* img = (uint4*)WfTi;
#pragma unroll
    for (int i = 0; i < 2; ++i) {
        int u = t + 256 * i;
        int al = u >> 3, q = u & 7;
        int a = a0 + al;
        int ks = tk * 2 + (q >> 2);
        int qq = q & 3;
        img[ks * 1024 + a * 4 + (qq ^ ((a >> 1) & 3))] =
            *(const uint4*)(&tl[al * 80 + q * 8]);
    }
}

// ---- hb[b][a] = hidden[b]·Wh[:,a] + bh[a] + bf[a] ----
__global__ void hb_kernel(const float* __restrict__ hidden, const float* __restrict__ Wh,
                          const float* __restrict__ bh, const float* __restrict__ bfv,
                          float* __restrict__ hb) {
    const int b = blockIdx.x, a = threadIdx.x;
    float acc = bh[a] + bfv[a];
    const float* hrow = hidden + b * 512;
#pragma unroll 8
    for (int d = 0; d < 512; ++d)
        acc += hrow[d] * Wh[d * 256 + a];
    hb[b * 256 + a] = acc;
}

// ---- S: 8192 tiles x 16 rows, 512 thr, 8 waves (wave = 16 rows x 32 cols).
// A staged f32 by global_load_lds with PRE-SWIZZLED source (zero registers,
// all issues in flight together); f32->bf16 cvt at ds_read time. B streamed
// per-wave by gld_lds 3-buffer with counted vmcnt(2). No barriers in K-loop.
__launch_bounds__(512, 4)
__global__ void scores_kernel(const float* __restrict__ feats,
                              const unsigned short* __restrict__ WfTi,
                              const float* __restrict__ hbg,
                              const float* __restrict__ Ws,
                              float* __restrict__ scores,
                              float* __restrict__ stats) {
    extern __shared__ char smem[];
    char* Ab = smem;                         // [16][2048 B] f32, 16B-XOR swizzled
    char* Bb = smem + 32768;                 // 8 waves x 3 x 2048 B

    const int t = threadIdx.x;
    const int tile = blockIdx.x;
    const int b = tile >> 8;                 // 256 tiles per batch
    const int row0 = tile * 16;
    const int lane = t & 63, w = t >> 6;     // wave w owns cols w*32..+31
    const int lr = lane & 15, lg = lane >> 4;

    char* bw = Bb + w * 6144;                // wave-private 3-buffer
    const char* bimg = (const char*)WfTi + w * 2048 + lane * 16;

    // B(0), B(1) in flight
    gld_lds16(bimg,                bw);
    gld_lds16(bimg + 1024,         bw + 1024);
    gld_lds16(bimg + 16384,        bw + 2048);
    gld_lds16(bimg + 16384 + 1024, bw + 3072);

    // A stage: 4 fire-and-forget issues per wave, source pre-swizzled so the
    // linear LDS write yields LDS[r][X] = feats[r][X ^ ((r&7)<<4)] per 16B block
    {
        const char* fbase = (const char*)feats + (size_t)row0 * 2048;
#pragma unroll
        for (int q = 0; q < 4; ++q) {
            int idx = w * 4 + q;             // 0..31 = (row, half)
            int r = idx >> 1, h = idx & 1;
            int soff = (h * 1024 + lane * 16) ^ ((r & 7) << 4);
            gld_lds16(fbase + (size_t)r * 2048 + soff, Ab + r * 2048 + h * 1024);
        }
    }

    // epilogue operands (retire with the drain below)
    float hbv[2], wsv[2];
#pragma unroll
    for (int j = 0; j < 2; ++j) {
        int col = w * 32 + j * 16 + lr;
        hbv[j] = hbg[b * 256 + col];
        wsv[j] = Ws[col];
    }

    asm volatile("s_waitcnt vmcnt(0)" ::: "memory");   // A (and B0/B1) resident
    __builtin_amdgcn_s_barrier();

    const int asw = (lr & 7) << 4;
    f32x4 acc[2] = {};
#pragma unroll
    for (int ks = 0; ks < 16; ++ks) {
        if (ks < 15) { asm volatile("s_waitcnt vmcnt(2)" ::: "memory"); }
        else         { asm volatile("s_waitcnt vmcnt(0)" ::: "memory"); }
        char* bcur = bw + (ks % 3) * 2048;
        if (ks < 14) {                       // keep 2 chunks ahead in flight
            const char* bs = bimg + (size_t)(ks + 2) * 16384;
            char* bnx = bw + ((ks + 2) % 3) * 2048;
            gld_lds16(bs,        bnx);
            gld_lds16(bs + 1024, bnx + 1024);
        }
        // A frag: row=lr, k=ks*32+lg*8 — two f32x4 reads, cvt to bf16
        int y = ks * 128 + lg * 32;
        float4 x0 = *(const float4*)(Ab + lr * 2048 + ((y)      ^ asw));
        float4 x1 = *(const float4*)(Ab + lr * 2048 + ((y + 16) ^ asw));
        short8 af = cvt8(x0, x1);
        short8 bf[2];
#pragma unroll
        for (int j = 0; j < 2; ++j) {
            int lc = j * 16 + lr;
            bf[j] = *(const short8*)(bcur + lc * 64 + ((lg * 16) ^ (((lc >> 1) & 3) << 4)));
        }
        acc[0] = __builtin_amdgcn_mfma_f32_16x16x32_bf16(af, bf[0], acc[0], 0, 0, 0);
        acc[1] = __builtin_amdgcn_mfma_f32_16x16x32_bf16(af, bf[1], acc[1], 0, 0, 0);
    }

    // scores = sum_a tanh(C + hb[a]) * Ws[a]; C frag: col=lr, row=lg*4+r
    float* wpw = (float*)(Bb + w * 6144);    // wave-own region (done with B reads)
#pragma unroll
    for (int r = 0; r < 4; ++r) {
        float p = fast_tanh(acc[0][r] + hbv[0]) * wsv[0]
                + fast_tanh(acc[1][r] + hbv[1]) * wsv[1];
#pragma unroll
        for (int off = 1; off < 16; off <<= 1) p += __shfl_xor(p, off, 64);
        if (lr == 0) wpw[lg * 4 + r] = p;
    }
    lds_barrier();

    // per-tile softmax stats (first 16 lanes)
    if (t < 16) {
        float s = 0.f;
#pragma unroll
        for (int k = 0; k < 8; ++k) s += ((const float*)(Bb + k * 6144))[t];
        scores[row0 + t] = s;
        float m = s;
#pragma unroll
        for (int off = 1; off < 16; off <<= 1) m = fmaxf(m, __shfl_xor(m, off, 16));
        float e = __expf(s - m);
        float l = e;
#pragma unroll
        for (int off = 1; off < 16; off <<= 1) l += __shfl_xor(l, off, 16);
        if (t == 0) { stats[tile * 2] = m; stats[tile * 2 + 1] = l; }
    }
}

// ---- C: ctx partials over 16-row tiles — pure feats stream (proven regime) ----
__launch_bounds__(256, 8)
__global__ void ctx_kernel(const float* __restrict__ feats,
                           const float* __restrict__ scores,
                           const float* __restrict__ stats,
                           float* __restrict__ ctxp) {
    __shared__ float wbuf[16];
    const int tile = blockIdx.x;
    const int row0 = tile * 16;
    const int t = threadIdx.x;

    if (t < 16) wbuf[t] = __expf(scores[row0 + t] - stats[tile * 2]);
    __syncthreads();

    const float* fb = feats + (size_t)row0 * 512 + t * 2;
    float accx = 0.f, accy = 0.f;
#pragma unroll
    for (int n0 = 0; n0 < 16; n0 += 8) {
        float2 v[8]; float sc[8];
#pragma unroll
        for (int u = 0; u < 8; ++u) {
            sc[u] = wbuf[n0 + u];
            v[u]  = *(const float2*)(fb + (size_t)(n0 + u) * 512);
        }
#pragma unroll
        for (int u = 0; u < 8; ++u) { accx += sc[u] * v[u].x; accy += sc[u] * v[u].y; }
    }
    float2 o; o.x = accx; o.y = accy;
    *(float2*)(ctxp + (size_t)tile * 512 + t * 2) = o;
}

// ---- per-batch: global softmax over 256 partials + alpha + ctx merge.
// 64 blocks = 32 batches x 2 d-halves (2x TLP on the merge loop). ----
__global__ void combine_kernel(const float* __restrict__ scores,
                               const float* __restrict__ stats,
                               const float* __restrict__ ctxp,
                               float* __restrict__ out_ctx,
                               float* __restrict__ out_alpha) {
    __shared__ float scales[256];
    __shared__ float red[4];
    const int b = blockIdx.x >> 1, dh = blockIdx.x & 1;
    const int t = threadIdx.x;

    float mk = stats[(b * 256 + t) * 2];
    float lk = stats[(b * 256 + t) * 2 + 1];
    float M = mk;
#pragma unroll
    for (int off = 1; off < 64; off <<= 1) M = fmaxf(M, __shfl_xor(M, off, 64));
    if ((t & 63) == 0) red[t >> 6] = M;
    __syncthreads();
    M = fmaxf(fmaxf(red[0], red[1]), fmaxf(red[2], red[3]));
    float e = __expf(mk - M);
    float z = e * lk;
#pragma unroll
    for (int off = 1; off < 64; off <<= 1) z += __shfl_xor(z, off, 64);
    __syncthreads();
    if ((t & 63) == 0) red[t >> 6] = z;
    __syncthreads();
    const float Z = red[0] + red[1] + red[2] + red[3];
    scales[t] = e / Z;
    __syncthreads();

    const float invZ = 1.0f / Z;
    const float* sb = scores + b * 4096;
    float* abp = out_alpha + b * 4096;
#pragma unroll
    for (int i = 0; i < 8; ++i) {            // this block's 2048 alphas
        int n = dh * 2048 + t + 256 * i;
        abp[n] = __expf(sb[n] - M) * invZ;
    }
    // ctx merge: this block's 256 d-cols, 8-wide unrolled over 256 partials
    const int d = dh * 256 + t;
    const float* cb = ctxp + (size_t)b * 256 * 512 + d;
    float acc = 0.f;
    for (int k0 = 0; k0 < 256; k0 += 8) {
        float v[8]; float s[8];
#pragma unroll
        for (int u = 0; u < 8; ++u) {
            s[u] = scales[k0 + u];
            v[u] = cb[(size_t)(k0 + u) * 512];
        }
#pragma unroll
        for (int u = 0; u < 8; ++u) acc += s[u] * v[u];
    }
    out_ctx[b * 512 + d] = acc;
}

extern "C" void kernel_launch(void* const* d_in, const int* in_sizes, int n_in,
                              void* d_out, int out_size, void* d_ws, size_t ws_size,
                              hipStream_t stream) {
    (void)in_sizes; (void)n_in; (void)out_size; (void)ws_size;
    const float* feats  = (const float*)d_in[0];
    const float* hidden = (const float*)d_in[1];
    const float* Wf     = (const float*)d_in[2];
    const float* bfv    = (const float*)d_in[3];
    const float* Wh     = (const float*)d_in[4];
    const float* bh     = (const float*)d_in[5];
    const float* Ws     = (const float*)d_in[6];
    // d_in[7] (bs) irrelevant: softmax is shift-invariant and scores are not output.

    char* ws = (char*)d_ws;
    unsigned short* WfTi = (unsigned short*)(ws + WFT_OFF);
    float* hb     = (float*)(ws + HB_OFF);
    float* scores = (float*)(ws + SC_OFF);
    float* stats  = (float*)(ws + ST_OFF);
    float* ctxp   = (float*)(ws + CP_OFF);

    float* out_ctx   = (float*)d_out;
    float* out_alpha = out_ctx + 32 * 512;

    hipFuncSetAttribute((const void*)scores_kernel,
                        hipFuncAttributeMaxDynamicSharedMemorySize, SMEM_S);

    hipLaunchKernelGGL(wft_kernel, dim3(32), dim3(256), 0, stream, Wf, WfTi);
    hipLaunchKernelGGL(hb_kernel, dim3(32), dim3(256), 0, stream, hidden, Wh, bh, bfv, hb);
    hipLaunchKernelGGL(scores_kernel, dim3(8192), dim3(512), SMEM_S, stream,
                       feats, WfTi, hb, Ws, scores, stats);
    hipLaunchKernelGGL(ctx_kernel, dim3(8192), dim3(256), 0, stream,
                       feats, scores, stats, ctxp);
    hipLaunchKernelGGL(combine_kernel, dim3(64), dim3(256), 0, stream,
                       scores, stats, ctxp, out_ctx, out_alpha);
}

// Round 10
// 178.215 us; speedup vs baseline: 1.2477x; 1.2477x over previous
//
#include <hip/hip_runtime.h>
#include <hip/hip_bf16.h>

typedef __attribute__((ext_vector_type(8))) short short8;
typedef __attribute__((ext_vector_type(4))) float f32x4;

// ws layout (bytes)
#define IMG_OFF 0          // bf16 img[8 kc][256 col][128 B swz] = 262144
#define HB_OFF  262144     // f32[32*256]            =  32768
#define SC_OFF  294912     // f32[131072] scores     = 524288
#define ST_OFF  819200     // f32[1024*2] m,l        =   8192
#define CP_OFF  835584     // f32[1024*512] ctx part = 2097152  (total ~2.9 MB)

// scores LDS: Aa dbuf 2x[128][256B] @0 (64 KB), Bb dbuf 2x[256][128B] @65536 (64 KB),
//             wpart[4][128] @131072 (2 KB), wsum[4] @133120
#define SMEM_S 133184

__device__ __forceinline__ unsigned pack_bf16(float a, float b) {
    unsigned short sa = __builtin_bit_cast(unsigned short, __float2bfloat16(a));
    unsigned short sb = __builtin_bit_cast(unsigned short, __float2bfloat16(b));
    return (unsigned)sa | ((unsigned)sb << 16);
}
__device__ __forceinline__ short8 cvt8(float4 a, float4 b) {
    union { unsigned u[4]; short8 s; } r;
    r.u[0] = pack_bf16(a.x, a.y); r.u[1] = pack_bf16(a.z, a.w);
    r.u[2] = pack_bf16(b.x, b.y); r.u[3] = pack_bf16(b.z, b.w);
    return r.s;
}
__device__ __forceinline__ float fast_tanh(float x) {
    float e2 = __expf(2.0f * x);
    return 1.0f - 2.0f / (e2 + 1.0f);
}
__device__ __forceinline__ void lds_barrier() {
    asm volatile("s_waitcnt lgkmcnt(0)" ::: "memory");
    __builtin_amdgcn_s_barrier();
}
__device__ __forceinline__ void gld_lds16(const char* g, char* l) {
    __builtin_amdgcn_global_load_lds(
        (const __attribute__((address_space(1))) void*)g,
        (__attribute__((address_space(3))) void*)l, 16, 0, 0);
}

// ---- Wf (512x256 f32) -> bf16 img[kc][col][128B]: 16B block q of col a at
//      byte kc*32768 + a*128 + 16*(q ^ (a&7)).  (read-side swizzle baked in) ----
__global__ void wft_kernel(const float* __restrict__ Wf, char* __restrict__ img) {
    __shared__ unsigned short tl[64 * 80];
    const int t = threadIdx.x;
    const int tk = blockIdx.x >> 2, ta = blockIdx.x & 3;
    const int d0 = tk * 64, a0 = ta * 64;
#pragma unroll
    for (int i = 0; i < 16; ++i) {
        int flat = t + 256 * i;
        int dl = flat >> 6, al = flat & 63;
        tl[al * 80 + dl] = __builtin_bit_cast(unsigned short,
                               __float2bfloat16(Wf[(d0 + dl) * 256 + a0 + al]));
    }
    __syncthreads();
    uint4* out = (uint4*)img;
#pragma unroll
    for (int i = 0; i < 2; ++i) {
        int u = t + 256 * i;
        int al = u >> 3, q = u & 7;          // q: 16B block = 8 consecutive k
        int a = a0 + al;
        out[tk * 2048 + a * 8 + (q ^ (a & 7))] =
            *(const uint4*)(&tl[al * 80 + q * 8]);
    }
}

// ---- hb[b][a] = hidden[b]·Wh[:,a] + bh[a] + bf[a] ----
__global__ void hb_kernel(const float* __restrict__ hidden, const float* __restrict__ Wh,
                          const float* __restrict__ bh, const float* __restrict__ bfv,
                          float* __restrict__ hb) {
    const int b = blockIdx.x, a = threadIdx.x;
    float acc = bh[a] + bfv[a];
    const float* hrow = hidden + b * 512;
#pragma unroll 8
    for (int d = 0; d < 512; ++d)
        acc += hrow[d] * Wh[d * 256 + a];
    hb[b * 256 + a] = acc;
}

// ---- S: m97-structure GEMM. 1024 blocks x 128 rows x 256 cols, 512 thr.
// 8 K-chunks of 64; per chunk: drain+barrier -> issue next chunk's A(f32)+B
// via global_load_lds (64 KB/CU continuously in flight) -> 32 MFMA/wave.
// Wave = 64 rows x 64 cols (4x4 16x16 frags). A cvt f32->bf16 at ds_read. ----
__launch_bounds__(512, 2)
__global__ void scores_kernel(const float* __restrict__ feats,
                              const char* __restrict__ img,
                              const float* __restrict__ hbg,
                              const float* __restrict__ Ws,
                              float* __restrict__ scores,
                              float* __restrict__ stats) {
    extern __shared__ char smem[];
    char* Aa     = smem;                     // [2][128][256 B] f32, 16B-XOR swz
    char* Bb     = smem + 65536;             // [2][256][128 B] bf16, pre-swz
    float* wpart = (float*)(smem + 131072);  // [4][128]
    float* wsum  = (float*)(smem + 133120);  // [4]

    const int t = threadIdx.x, blk = blockIdx.x;
    const int b = blk >> 5;                  // 32 tiles per batch
    const int row0 = blk * 128;
    const int lane = t & 63, w = t >> 6;
    const int wr = w >> 2, wc = w & 3;       // 2 row-groups x 4 col-groups
    const int lr = lane & 15, lg = lane >> 4;
    const int srow = lane >> 4, sq = lane & 15;

    const char* fbase = (const char*)feats + (size_t)row0 * 2048;

    // ---- stage chunk kc into buffer d: 4 A + 4 B gld_lds issues per wave ----
    auto STAGE = [&](int kc, int d) {
        char* Ad = Aa + d * 32768;
#pragma unroll
        for (int i = 0; i < 4; ++i) {
            int idx = w * 4 + i;             // covers rows idx*4 .. idx*4+3
            int r = idx * 4 + srow;
            gld_lds16(fbase + (size_t)r * 2048 + kc * 256 + ((sq ^ (r & 7)) << 4),
                      Ad + idx * 1024);
        }
        char* Bd = Bb + d * 32768 + w * 4096;
        const char* bs = img + kc * 32768 + w * 4096 + lane * 16;
#pragma unroll
        for (int i = 0; i < 4; ++i)
            gld_lds16(bs + i * 1024, Bd + i * 1024);
    };

    STAGE(0, 0);

    float hbv[4], wsv[4];
#pragma unroll
    for (int j = 0; j < 4; ++j) {
        int col = wc * 64 + j * 16 + lr;
        hbv[j] = hbg[b * 256 + col];
        wsv[j] = Ws[col];
    }

    f32x4 acc[4][4] = {};
    for (int kc = 0; kc < 8; ++kc) {
        asm volatile("s_waitcnt vmcnt(0) lgkmcnt(0)" ::: "memory");
        __builtin_amdgcn_s_barrier();        // chunk kc resident; buf^1 free
        if (kc < 7) STAGE(kc + 1, (kc + 1) & 1);   // flies under the MFMAs below
        const char* Ac = Aa + (kc & 1) * 32768;
        const char* Bc = Bb + (kc & 1) * 32768;
#pragma unroll
        for (int kk = 0; kk < 2; ++kk) {
            short8 af[4], bf[4];
#pragma unroll
            for (int i = 0; i < 4; ++i) {
                int rr = wr * 64 + i * 16 + lr;
                int sw = (rr & 7) << 4;
                int off = kk * 128 + lg * 32;
                float4 x0 = *(const float4*)(Ac + rr * 256 + (off ^ sw));
                float4 x1 = *(const float4*)(Ac + rr * 256 + ((off + 16) ^ sw));
                af[i] = cvt8(x0, x1);
            }
#pragma unroll
            for (int j = 0; j < 4; ++j) {
                int cc = wc * 64 + j * 16 + lr;
                bf[j] = *(const short8*)(Bc + cc * 128 +
                                         ((kk * 64 + lg * 16) ^ ((cc & 7) << 4)));
            }
#pragma unroll
            for (int i = 0; i < 4; ++i)
#pragma unroll
                for (int j = 0; j < 4; ++j)
                    acc[i][j] = __builtin_amdgcn_mfma_f32_16x16x32_bf16(
                        af[i], bf[j], acc[i][j], 0, 0, 0);
        }
    }

    // ---- epilogue: scores = sum_a tanh(C + hb[a]) * Ws[a] ----
    // C frag: col = lr, row = wr*64 + i*16 + lg*4 + r
#pragma unroll
    for (int i = 0; i < 4; ++i) {
#pragma unroll
        for (int r = 0; r < 4; ++r) {
            float p = 0.f;
#pragma unroll
            for (int j = 0; j < 4; ++j)
                p += fast_tanh(acc[i][j][r] + hbv[j]) * wsv[j];
#pragma unroll
            for (int off = 1; off < 16; off <<= 1) p += __shfl_xor(p, off, 64);
            if (lr == 0) wpart[wc * 128 + wr * 64 + i * 16 + lg * 4 + r] = p;
        }
    }
    lds_barrier();

    if (t < 128) {
        float s = wpart[t] + wpart[128 + t] + wpart[256 + t] + wpart[384 + t];
        scores[row0 + t] = s;
        float m = s;
#pragma unroll
        for (int off = 1; off < 64; off <<= 1) m = fmaxf(m, __shfl_xor(m, off, 64));
        float e = __expf(s - m);
        float l = e;
#pragma unroll
        for (int off = 1; off < 64; off <<= 1) l += __shfl_xor(l, off, 64);
        if ((t & 63) == 0) { wsum[(t >> 6) * 2] = m; wsum[(t >> 6) * 2 + 1] = l; }
    }
    lds_barrier();
    if (t == 0) {
        float m0 = wsum[0], l0 = wsum[1], m1 = wsum[2], l1 = wsum[3];
        float M = fmaxf(m0, m1);
        float L = l0 * __expf(m0 - M) + l1 * __expf(m1 - M);
        stats[blk * 2] = M; stats[blk * 2 + 1] = L;
    }
}

// ---- C: ctx partials over 128-row tiles — pure feats stream (L3-hot) ----
__launch_bounds__(256, 8)
__global__ void ctx_kernel(const float* __restrict__ feats,
                           const float* __restrict__ scores,
                           const float* __restrict__ stats,
                           float* __restrict__ ctxp) {
    __shared__ float wbuf[128];
    const int tile = blockIdx.x;
    const int row0 = tile * 128;
    const int t = threadIdx.x;

    if (t < 128) wbuf[t] = __expf(scores[row0 + t] - stats[tile * 2]);
    __syncthreads();

    const float* fb = feats + (size_t)row0 * 512 + t * 2;
    float accx = 0.f, accy = 0.f;
    for (int n0 = 0; n0 < 128; n0 += 8) {
        float2 v[8]; float sc[8];
#pragma unroll
        for (int u = 0; u < 8; ++u) {
            sc[u] = wbuf[n0 + u];
            v[u]  = *(const float2*)(fb + (size_t)(n0 + u) * 512);
        }
#pragma unroll
        for (int u = 0; u < 8; ++u) { accx += sc[u] * v[u].x; accy += sc[u] * v[u].y; }
    }
    float2 o; o.x = accx; o.y = accy;
    *(float2*)(ctxp + (size_t)tile * 512 + t * 2) = o;
}

// ---- per-batch: global softmax over 32 partials + alpha + ctx merge ----
__global__ void combine_kernel(const float* __restrict__ scores,
                               const float* __restrict__ stats,
                               const float* __restrict__ ctxp,
                               float* __restrict__ out_ctx,
                               float* __restrict__ out_alpha) {
    __shared__ float scales[32];
    __shared__ float MZ[2];
    const int b = blockIdx.x, t = threadIdx.x;
    if (t < 32) {
        float mk = stats[(b * 32 + t) * 2];
        float lk = stats[(b * 32 + t) * 2 + 1];
        float M = mk;
#pragma unroll
        for (int off = 1; off < 32; off <<= 1) M = fmaxf(M, __shfl_xor(M, off, 32));
        float e = __expf(mk - M);
        float z = lk * e;
#pragma unroll
        for (int off = 1; off < 32; off <<= 1) z += __shfl_xor(z, off, 32);
        scales[t] = e / z;
        if (t == 0) { MZ[0] = M; MZ[1] = z; }
    }
    __syncthreads();
    const float M = MZ[0], invZ = 1.0f / MZ[1];
    const float* sb = scores + b * 4096;
    float* abp = out_alpha + b * 4096;
#pragma unroll
    for (int i = 0; i < 16; ++i) {
        int n = t + 256 * i;
        abp[n] = __expf(sb[n] - M) * invZ;
    }
    const int d0 = t * 2;
    const float* cb = ctxp + (size_t)b * 32 * 512;
    float accx = 0.f, accy = 0.f;
    for (int k0 = 0; k0 < 32; k0 += 8) {
        float2 v[8]; float s[8];
#pragma unroll
        for (int u = 0; u < 8; ++u) {
            s[u] = scales[k0 + u];
            v[u] = *(const float2*)(cb + (size_t)(k0 + u) * 512 + d0);
        }
#pragma unroll
        for (int u = 0; u < 8; ++u) { accx += s[u] * v[u].x; accy += s[u] * v[u].y; }
    }
    float2 o; o.x = accx; o.y = accy;
    *(float2*)(out_ctx + b * 512 + d0) = o;
}

extern "C" void kernel_launch(void* const* d_in, const int* in_sizes, int n_in,
                              void* d_out, int out_size, void* d_ws, size_t ws_size,
                              hipStream_t stream) {
    (void)in_sizes; (void)n_in; (void)out_size; (void)ws_size;
    const float* feats  = (const float*)d_in[0];
    const float* hidden = (const float*)d_in[1];
    const float* Wf     = (const float*)d_in[2];
    const float* bfv    = (const float*)d_in[3];
    const float* Wh     = (const float*)d_in[4];
    const float* bh     = (const float*)d_in[5];
    const float* Ws     = (const float*)d_in[6];
    // d_in[7] (bs) irrelevant: softmax is shift-invariant and scores are not output.

    char* ws = (char*)d_ws;
    char*  img    = ws + IMG_OFF;
    float* hb     = (float*)(ws + HB_OFF);
    float* scores = (float*)(ws + SC_OFF);
    float* stats  = (float*)(ws + ST_OFF);
    float* ctxp   = (float*)(ws + CP_OFF);

    float* out_ctx   = (float*)d_out;
    float* out_alpha = out_ctx + 32 * 512;

    hipFuncSetAttribute((const void*)scores_kernel,
                        hipFuncAttributeMaxDynamicSharedMemorySize, SMEM_S);

    hipLaunchKernelGGL(wft_kernel, dim3(32), dim3(256), 0, stream, Wf, img);
    hipLaunchKernelGGL(hb_kernel, dim3(32), dim3(256), 0, stream, hidden, Wh, bh, bfv, hb);
    hipLaunchKernelGGL(scores_kernel, dim3(1024), dim3(512), SMEM_S, stream,
                       feats, img, hb, Ws, scores, stats);
    hipLaunchKernelGGL(ctx_kernel, dim3(1024), dim3(256), 0, stream,
                       feats, scores, stats, ctxp);
    hipLaunchKernelGGL(combine_kernel, dim3(32), dim3(256), 0, stream,
                       scores, stats, ctxp, out_ctx, out_alpha);
}